// Round 11
// baseline (215.361 us; speedup 1.0000x reference)
//
#include <hip/hip_runtime.h>

#define BINS 5
#define PTS  2
constexpr int Bx = 2, Cc = 256, Hh = 100, Ww = 152;
constexpr int HW = Hh * Ww;          // 15200
constexpr int NTILE = 238;           // merge pixel tiles (64 px each)
constexpr float EPS_DIV = 1e-6f;
constexpr float GN_EPS  = 1e-5f;

typedef __attribute__((ext_vector_type(8))) short bfrag;   // 8 bf16 (4 VGPRs)
typedef __attribute__((ext_vector_type(4))) float f32x4;   // MFMA C/D

__device__ __forceinline__ ushort f2bf(float f) {
    union { float f; unsigned u; } v; v.f = f;
    unsigned r = v.u + 0x7fffu + ((v.u >> 16) & 1u);
    return (ushort)(r >> 16);
}
__device__ __forceinline__ float bflo(unsigned u) {
    return __uint_as_float(u << 16);
}
__device__ __forceinline__ float bfhi(unsigned u) {
    return __uint_as_float(u & 0xffff0000u);
}
__device__ __forceinline__ unsigned pack2(float a, float b) {
    return (unsigned)f2bf(a) | ((unsigned)f2bf(b) << 16);
}

// ---------------------------------------------------------------------------
// K0: transpose+convert x[b][c][hw] fp32 -> xbt[b][hw][c] bf16
// ---------------------------------------------------------------------------
__global__ __launch_bounds__(256)
void k_xt(const float* __restrict__ x, ushort* __restrict__ xbt)
{
    __shared__ float tile[32][33];
    const int t = threadIdx.x;
    const int hw0 = blockIdx.x * 32;
    const int c0 = blockIdx.y * 32;
    const int b = blockIdx.z;
    const float* xb = x + ((size_t)b * Cc + c0) * HW + hw0;
    const int tx = t & 31, ty = t >> 5;
    #pragma unroll
    for (int r = 0; r < 4; r++) {
        int c = ty + r * 8;
        tile[c][tx] = xb[(size_t)c * HW + tx];
    }
    __syncthreads();
    const int hwl = t >> 3, c4 = (t & 7) * 4;
    ushort4 o = { f2bf(tile[c4 + 0][hwl]), f2bf(tile[c4 + 1][hwl]),
                  f2bf(tile[c4 + 2][hwl]), f2bf(tile[c4 + 3][hwl]) };
    *(ushort4*)&xbt[((size_t)b * HW + hw0 + hwl) * Cc + c0 + c4] = o;
}

// ---------------------------------------------------------------------------
// K1: combined weights (fp32 accumulate, bf16 store).
//  which=0: Wh[p][dd][c] = sum_d w1[p][dd][d] * efw[p*256+d][c]
//  which=1: Cm[co][p*256+c] = sum_d mw[co][p*256+d] * efw[p*256+d][c]
// grid (16 row-tiles, 2 p, 2 which), thread = output column c.
// ---------------------------------------------------------------------------
__global__ __launch_bounds__(256)
void k_wcomb(const float* __restrict__ efw, const float* __restrict__ w1,
             const float* __restrict__ mw, ushort* __restrict__ whb,
             ushort* __restrict__ cmb)
{
    __shared__ float Wt[16][256];
    const int t = threadIdx.x;
    const int tile = blockIdx.x, p = blockIdx.y, which = blockIdx.z;
    if (which == 0) {
        const float* src = w1 + (size_t)p * 65536 + (size_t)tile * 16 * 256;
        #pragma unroll
        for (int i = 0; i < 16; i++) Wt[i][t] = src[i * 256 + t];
    } else {
        #pragma unroll
        for (int i = 0; i < 16; i++)
            Wt[i][t] = mw[((size_t)(tile * 16 + i)) * 512 + p * 256 + t];
    }
    __syncthreads();
    float acc[16];
    #pragma unroll
    for (int r = 0; r < 16; r++) acc[r] = 0.f;
    const float* eb = efw + (size_t)p * 256 * 256;
    for (int d = 0; d < 256; d++) {
        float v = eb[(size_t)d * 256 + t];
        #pragma unroll
        for (int r = 0; r < 16; r++) acc[r] += Wt[r][d] * v;
    }
    if (which == 0) {
        #pragma unroll
        for (int r = 0; r < 16; r++)
            whb[(size_t)p * 65536 + (size_t)(tile * 16 + r) * 256 + t] = f2bf(acc[r]);
    } else {
        #pragma unroll
        for (int r = 0; r < 16; r++)
            cmb[(size_t)(tile * 16 + r) * 512 + p * 256 + t] = f2bf(acc[r]);
    }
}

// ---------------------------------------------------------------------------
// K2: bias folds.  hbias[p][dd] = w1[p][dd]·efb_p + b1[p][dd];
//                  vb[p][co]    = mw[co][p-half]·efb_p.     grid(4).
// ---------------------------------------------------------------------------
__global__ __launch_bounds__(256)
void k_vbias(const float* __restrict__ efb, const float* __restrict__ w1,
             const float* __restrict__ b1, const float* __restrict__ mw,
             float* __restrict__ hbias, float* __restrict__ vb)
{
    __shared__ float eb[256];
    const int t = threadIdx.x;
    const int which = blockIdx.x >> 1, p = blockIdx.x & 1;
    eb[t] = efb[p * 256 + t];
    __syncthreads();
    float a = 0.f;
    if (which == 0) {
        const float* row = w1 + ((size_t)p * 256 + t) * 256;
        for (int d = 0; d < 256; d++) a += row[d] * eb[d];
        hbias[p * 256 + t] = a + b1[p * 256 + t];
    } else {
        const float* row = mw + (size_t)t * 512 + p * 256;
        for (int d = 0; d < 256; d++) a += row[d] * eb[d];
        vb[p * 256 + t] = a;
    }
}

// ---------------------------------------------------------------------------
// K3: heat[b][p][pix] = exp(sum_d w2[d]*relu((Wh@x)[d][pix]+hbias[d]) + b2)
// A = Wh[p] (bf16 [d][c]), B = xbt tiles.  Round-4 proven tile structure.
// ---------------------------------------------------------------------------
__global__ __launch_bounds__(256)
void k_heat(const ushort* __restrict__ xbt, const ushort* __restrict__ whb,
            const float* __restrict__ hbias, const float* __restrict__ w2,
            const float* __restrict__ b2, float* __restrict__ heat)
{
    __shared__ ushort As[256 * 72];
    __shared__ ushort Bs[64 * 72];
    __shared__ float red[4][64];
    const int t = threadIdx.x;
    const int wv = t >> 6, ln = t & 63;
    const int quad = ln >> 4, l16 = ln & 15;
    const int pix0 = blockIdx.x * 64;
    const int p = blockIdx.y;
    const int b = blockIdx.z;
    const ushort* xb = xbt + (size_t)b * HW * Cc;
    const ushort* w1p = whb + (size_t)p * Cc * Cc;

    f32x4 acc[4][4];
    #pragma unroll
    for (int i = 0; i < 4; i++)
        #pragma unroll
        for (int j = 0; j < 4; j++) acc[i][j] = (f32x4){0.f, 0.f, 0.f, 0.f};

    const int srow = t >> 3, scol = (t & 7) * 8;

    for (int k0 = 0; k0 < 256; k0 += 64) {
        #pragma unroll
        for (int r = 0; r < 8; r++) {
            int row = srow + r * 32;
            *(uint4*)&As[row * 72 + scol] =
                *(const uint4*)&w1p[(size_t)row * 256 + k0 + scol];
        }
        #pragma unroll
        for (int r = 0; r < 2; r++) {
            int row = srow + r * 32;
            int pq = pix0 + row; if (pq > HW - 1) pq = HW - 1;
            *(uint4*)&Bs[row * 72 + scol] =
                *(const uint4*)&xb[(size_t)pq * Cc + k0 + scol];
        }
        __syncthreads();
        #pragma unroll
        for (int kk = 0; kk < 64; kk += 32) {
            bfrag af[4], bfr[4];
            #pragma unroll
            for (int dt = 0; dt < 4; dt++)
                af[dt] = *(const bfrag*)&As[(wv * 64 + dt * 16 + l16) * 72 + kk + quad * 8];
            #pragma unroll
            for (int pt = 0; pt < 4; pt++)
                bfr[pt] = *(const bfrag*)&Bs[(pt * 16 + l16) * 72 + kk + quad * 8];
            #pragma unroll
            for (int dt = 0; dt < 4; dt++)
                #pragma unroll
                for (int pt = 0; pt < 4; pt++)
                    acc[dt][pt] = __builtin_amdgcn_mfma_f32_16x16x32_bf16(
                        af[dt], bfr[pt], acc[dt][pt], 0, 0, 0);
        }
        __syncthreads();
    }

    const float* b1p = hbias + p * 256;
    const float* w2p = w2 + p * 256;
    float s[4] = {0.f, 0.f, 0.f, 0.f};
    #pragma unroll
    for (int dt = 0; dt < 4; dt++) {
        int chb = wv * 64 + dt * 16 + quad * 4;
        float bb[4], ww[4];
        #pragma unroll
        for (int r = 0; r < 4; r++) { bb[r] = b1p[chb + r]; ww[r] = w2p[chb + r]; }
        #pragma unroll
        for (int pt = 0; pt < 4; pt++)
            #pragma unroll
            for (int r = 0; r < 4; r++) {
                float h = acc[dt][pt][r] + bb[r];
                h = h > 0.f ? h : 0.f;
                s[pt] += ww[r] * h;
            }
    }
    #pragma unroll
    for (int pt = 0; pt < 4; pt++) {
        s[pt] += __shfl_xor(s[pt], 16);
        s[pt] += __shfl_xor(s[pt], 32);
    }
    if (ln < 16) {
        #pragma unroll
        for (int pt = 0; pt < 4; pt++) red[wv][pt * 16 + ln] = s[pt];
    }
    __syncthreads();
    if (t < 64) {
        float v = red[0][t] + red[1][t] + red[2][t] + red[3][t] + b2[p];
        int m = pix0 + t;
        if (m < HW) heat[(size_t)(b * PTS + p) * HW + m] = expf(v);
    }
}

// ---------------------------------------------------------------------------
// K4: sampling gathers X (not ef!): outs[b][pix][p*256+c] = g_p/denom (bf16),
// sbuf[b][p][pix] = h_p/denom.  uint4 gathers from 15.5MB xbt (L2-banded).
// ---------------------------------------------------------------------------
__global__ __launch_bounds__(256)
void k_sample(const ushort* __restrict__ xbt, const float* __restrict__ heat,
              const float* __restrict__ offs, ushort* __restrict__ outs,
              float* __restrict__ sbuf)
{
    __shared__ uint2 s_wo[32][20];
    const int t = threadIdx.x;
    const int bid = blockIdx.x;
    const int nx = (bid & 7) * 60 + (bid >> 3);
    if (nx >= 475) return;
    const int m0 = nx * 32;
    const int p = blockIdx.y;
    const int b = blockIdx.z;
    const float* heat_bp = heat + (size_t)(b * PTS + p) * HW;

    if (t < 32 * BINS) {
        int j = t / BINS, k = t % BINS;
        int hw = m0 + j;
        int hh = hw / Ww, ww = hw % Ww;
        int chy = (p * BINS + k) * 2;
        float oy = offs[((size_t)b * (PTS * BINS * 2) + chy)     * HW + hw];
        float ox = offs[((size_t)b * (PTS * BINS * 2) + chy + 1) * HW + hw];
        float ysf = (float)hh + oy;
        float xsf = (float)ww + ox;
        float y0 = floorf(ysf), x0 = floorf(xsf);
        #pragma unroll
        for (int dy = 0; dy < 2; dy++)
            #pragma unroll
            for (int dx = 0; dx < 2; dx++) {
                float yi = y0 + dy, xi = x0 + dx;
                float wgt = (1.f - fabsf(ysf - yi)) * (1.f - fabsf(xsf - xi));
                bool valid = (yi >= 0.f) && (yi <= (float)(Hh - 1)) &&
                             (xi >= 0.f) && (xi <= (float)(Ww - 1));
                int yc = (int)yi; yc = yc < 0 ? 0 : (yc > Hh - 1 ? Hh - 1 : yc);
                int xc = (int)xi; xc = xc < 0 ? 0 : (xc > Ww - 1 ? Ww - 1 : xc);
                int idx = yc * Ww + xc;
                float wh = valid ? wgt * heat_bp[idx] : 0.f;
                s_wo[j][k * 4 + dy * 2 + dx] =
                    make_uint2(__float_as_uint(wh), (unsigned)idx << 9);
            }
    }
    __syncthreads();
    if (t < 32) {
        float s = 0.f;
        #pragma unroll
        for (int u = 0; u < 20; u++) s += __uint_as_float(s_wo[t][u].x);
        float inv = 1.f / (s + EPS_DIV);
        #pragma unroll
        for (int u = 0; u < 20; u++)
            s_wo[t][u].x = __float_as_uint(__uint_as_float(s_wo[t][u].x) * inv);
        sbuf[(size_t)(b * PTS + p) * HW + m0 + t] = s * inv;   // h/(h+eps)
    }
    __syncthreads();

    // lane-half = pixel, lane&31 = 8-channel group; gather from xbt
    const int wv = t >> 6, ln = t & 63;
    const int half = ln >> 5, c8 = ln & 31;
    const char* efbase = (const char*)(xbt + (size_t)b * HW * Cc) + c8 * 16;
    ushort* ob = outs + ((size_t)(b * HW + m0)) * (PTS * Cc) + p * Cc + c8 * 8;
    #pragma unroll
    for (int i = 0; i < 8; i += 2) {
        const int j = wv * 8 + i + half;
        float a[8] = {0.f, 0.f, 0.f, 0.f, 0.f, 0.f, 0.f, 0.f};
        #pragma unroll
        for (int u = 0; u < 20; u++) {
            uint2 wo = s_wo[j][u];
            uint4 v = *(const uint4*)(efbase + wo.y);
            float w = __uint_as_float(wo.x);
            a[0] += w * bflo(v.x); a[1] += w * bfhi(v.x);
            a[2] += w * bflo(v.y); a[3] += w * bfhi(v.y);
            a[4] += w * bflo(v.z); a[5] += w * bfhi(v.z);
            a[6] += w * bflo(v.w); a[7] += w * bfhi(v.w);
        }
        uint4 o = { pack2(a[0], a[1]), pack2(a[2], a[3]),
                    pack2(a[4], a[5]), pack2(a[6], a[7]) };
        *(uint4*)(ob + (size_t)j * (PTS * Cc)) = o;
    }
}

// ---------------------------------------------------------------------------
// K5: mgb (bf16) = Cm @ outs + mb + vb0*s0 + vb1*s1; GN partials (no atomics)
// ---------------------------------------------------------------------------
__global__ __launch_bounds__(256)
void k_merge(const ushort* __restrict__ outs, const ushort* __restrict__ cmb,
             const float* __restrict__ mb, const float* __restrict__ vb,
             const float* __restrict__ sbuf, ushort* __restrict__ mgb,
             float* __restrict__ part2)
{
    __shared__ ushort As[64 * 72];      // [n][k]
    __shared__ ushort Bs[64 * 72];      // [pix][k]
    const int t = threadIdx.x;
    const int wv = t >> 6, ln = t & 63;
    const int quad = ln >> 4, l16 = ln & 15;
    const int pix0 = blockIdx.x * 64;
    const int n0 = blockIdx.y * 64;
    const int b = blockIdx.z;
    const ushort* ob = outs + (size_t)b * HW * (PTS * Cc);

    f32x4 acc[4];
    #pragma unroll
    for (int j = 0; j < 4; j++) acc[j] = (f32x4){0.f, 0.f, 0.f, 0.f};

    const int srow = t >> 3, scol = (t & 7) * 8;   // srow 0..31

    for (int k0 = 0; k0 < 512; k0 += 64) {
        #pragma unroll
        for (int r = 0; r < 2; r++) {
            int row = srow + r * 32;
            *(uint4*)&As[row * 72 + scol] =
                *(const uint4*)&cmb[(size_t)(n0 + row) * 512 + k0 + scol];
        }
        #pragma unroll
        for (int r = 0; r < 2; r++) {
            int row = srow + r * 32;
            int pq = pix0 + row; if (pq > HW - 1) pq = HW - 1;
            *(uint4*)&Bs[row * 72 + scol] =
                *(const uint4*)&ob[(size_t)pq * (PTS * Cc) + k0 + scol];
        }
        __syncthreads();
        #pragma unroll
        for (int kk = 0; kk < 64; kk += 32) {
            bfrag af = *(const bfrag*)&As[(wv * 16 + l16) * 72 + kk + quad * 8];
            #pragma unroll
            for (int pt = 0; pt < 4; pt++) {
                bfrag bfr = *(const bfrag*)&Bs[(pt * 16 + l16) * 72 + kk + quad * 8];
                acc[pt] = __builtin_amdgcn_mfma_f32_16x16x32_bf16(
                    af, bfr, acc[pt], 0, 0, 0);
            }
        }
        __syncthreads();
    }

    const int ch = n0 + wv * 16 + quad * 4;
    float bias[4], v0[4], v1[4];
    #pragma unroll
    for (int r = 0; r < 4; r++) {
        bias[r] = mb[ch + r];
        v0[r] = vb[ch + r];
        v1[r] = vb[256 + ch + r];
    }
    const float* s0p = sbuf + (size_t)(b * PTS + 0) * HW;
    const float* s1p = sbuf + (size_t)(b * PTS + 1) * HW;

    float sacc = 0.f, qacc = 0.f;
    #pragma unroll
    for (int pt = 0; pt < 4; pt++) {
        int pix = pix0 + pt * 16 + l16;
        if (pix < HW) {
            float s0 = s0p[pix], s1 = s1p[pix];
            #pragma unroll
            for (int r = 0; r < 4; r++) {
                float v = acc[pt][r] + bias[r] + v0[r] * s0 + v1[r] * s1;
                mgb[((size_t)b * Cc + ch + r) * HW + pix] = f2bf(v);
                sacc += v; qacc += v * v;
            }
        }
    }
    #pragma unroll
    for (int off = 1; off <= 16; off <<= 1) {
        sacc += __shfl_xor(sacc, off);
        qacc += __shfl_xor(qacc, off);
    }
    if ((ln & 31) == 0) {
        int g = (n0 >> 3) + wv * 2 + (quad >> 1);
        size_t idx = ((size_t)(b * 32 + g) * NTILE + blockIdx.x) * 2;
        part2[idx + 0] = sacc;
        part2[idx + 1] = qacc;
    }
}

// ---------------------------------------------------------------------------
// K6: reduce per-tile GN partials -> mean/istd per (b,group).  64 blocks.
// ---------------------------------------------------------------------------
__global__ __launch_bounds__(256)
void k_gnfinal(const float* __restrict__ part2, float* __restrict__ statf)
{
    const int bg = blockIdx.x;           // 0..63
    const int t = threadIdx.x;
    float s = 0.f, q = 0.f;
    if (t < NTILE) {
        s = part2[((size_t)bg * NTILE + t) * 2 + 0];
        q = part2[((size_t)bg * NTILE + t) * 2 + 1];
    }
    #pragma unroll
    for (int off = 1; off <= 32; off <<= 1) {
        s += __shfl_xor(s, off);
        q += __shfl_xor(q, off);
    }
    __shared__ float rs[4], rq[4];
    int wid = t >> 6;
    if ((t & 63) == 0) { rs[wid] = s; rq[wid] = q; }
    __syncthreads();
    if (t == 0) {
        float S = rs[0] + rs[1] + rs[2] + rs[3];
        float Q = rq[0] + rq[1] + rq[2] + rq[3];
        const float n = 8.f * HW;
        float mean = S / n;
        float var  = Q / n - mean * mean;
        statf[bg * 2 + 0] = mean;
        statf[bg * 2 + 1] = rsqrtf(var + GN_EPS);
    }
}

// ---------------------------------------------------------------------------
// K7: apply GN scale/shift + ReLU: read bf16 mgb, write fp32 out
// ---------------------------------------------------------------------------
__global__ __launch_bounds__(256)
void k_gnapply(const ushort* __restrict__ mgb, const float* __restrict__ statf,
               const float* __restrict__ gg, const float* __restrict__ gb,
               float* __restrict__ out)
{
    const int i8 = blockIdx.x * 256 + threadIdx.x;   // 3800 blocks exact
    const int i = i8 * 8;
    const int CHW = Cc * HW;
    const int b = i / CHW;
    const int r = i - b * CHW;
    const int c = r / HW;
    const int g = c >> 3;
    float mean = statf[(b * 32 + g) * 2 + 0];
    float istd = statf[(b * 32 + g) * 2 + 1];
    float sc = istd * gg[c];
    float sh = gb[c] - mean * sc;
    uint4 v = *(const uint4*)(mgb + i);
    float4 o0, o1;
    o0.x = fmaxf(bflo(v.x) * sc + sh, 0.f);
    o0.y = fmaxf(bfhi(v.x) * sc + sh, 0.f);
    o0.z = fmaxf(bflo(v.y) * sc + sh, 0.f);
    o0.w = fmaxf(bfhi(v.y) * sc + sh, 0.f);
    o1.x = fmaxf(bflo(v.z) * sc + sh, 0.f);
    o1.y = fmaxf(bfhi(v.z) * sc + sh, 0.f);
    o1.z = fmaxf(bflo(v.w) * sc + sh, 0.f);
    o1.w = fmaxf(bfhi(v.w) * sc + sh, 0.f);
    *(float4*)(out + i)     = o0;
    *(float4*)(out + i + 4) = o1;
}

// ---------------------------------------------------------------------------
extern "C" void kernel_launch(void* const* d_in, const int* in_sizes, int n_in,
                              void* d_out, int out_size, void* d_ws, size_t ws_size,
                              hipStream_t stream)
{
    const float* x    = (const float*)d_in[0];
    const float* offs = (const float*)d_in[1];
    const float* efw  = (const float*)d_in[2];
    const float* efb  = (const float*)d_in[3];
    const float* w1   = (const float*)d_in[4];
    const float* b1   = (const float*)d_in[5];
    const float* w2   = (const float*)d_in[6];
    const float* b2   = (const float*)d_in[7];
    const float* mw   = (const float*)d_in[8];
    const float* mb   = (const float*)d_in[9];
    const float* gg   = (const float*)d_in[10];
    const float* gb   = (const float*)d_in[11];
    float* out = (float*)d_out;

    ushort* whb   = (ushort*)d_ws;                       // 2*256*256
    ushort* cmb   = whb + 131072;                        // 256*512
    ushort* xbt   = cmb + 131072;                        // B*HW*C bf16
    ushort* outsb = xbt + (size_t)Bx * HW * Cc;          // B*HW*P*C bf16
    ushort* mgb   = outsb + (size_t)Bx * HW * PTS * Cc;  // B*C*HW bf16
    float*  heat  = (float*)(mgb + (size_t)Bx * Cc * HW);
    float*  sbuf  = heat + (size_t)Bx * PTS * HW;        // B*P*HW fp32
    float*  hbias = sbuf + (size_t)Bx * PTS * HW;        // 512
    float*  vb    = hbias + 512;                         // 512
    float*  part2 = vb + 512;                            // 64*NTILE*2
    float*  statf = part2 + (size_t)64 * NTILE * 2;      // 128

    dim3 blk(256);
    k_xt     <<<dim3(475, 8, Bx),   blk, 0, stream>>>(x, xbt);
    k_wcomb  <<<dim3(16, 2, 2),     blk, 0, stream>>>(efw, w1, mw, whb, cmb);
    k_vbias  <<<dim3(4),            blk, 0, stream>>>(efb, w1, b1, mw, hbias, vb);
    k_heat   <<<dim3(238, PTS, Bx), blk, 0, stream>>>(xbt, whb, hbias, w2, b2, heat);
    k_sample <<<dim3(480, PTS, Bx), blk, 0, stream>>>(xbt, heat, offs, outsb, sbuf);
    k_merge  <<<dim3(NTILE, 4, Bx), blk, 0, stream>>>(outsb, cmb, mb, vb, sbuf, mgb, part2);
    k_gnfinal<<<dim3(64),           blk, 0, stream>>>(part2, statf);
    k_gnapply<<<dim3(Bx * Cc * HW / 8 / 256), blk, 0, stream>>>(mgb, statf, gg, gb, out);
}